// Round 5
// baseline (169.599 us; speedup 1.0000x reference)
//
#include <hip/hip_runtime.h>
#include <math.h>

#define RED_BLOCKS 256
#define BLK 256
#define HDIM 64

typedef int   v4i __attribute__((ext_vector_type(4)));
typedef float v4f __attribute__((ext_vector_type(4)));

// ---------------- K1: per-block partial sum / sumsq (f64, deterministic) ----------------
__global__ void __launch_bounds__(BLK) k_reduce_partial(const float* __restrict__ hu, int n,
                                                        double* __restrict__ part) {
  __shared__ double ls[BLK];
  __shared__ double lq[BLK];
  const v4f* hu4 = (const v4f*)hu;
  const int n4 = n >> 2;
  double s = 0.0, q = 0.0;
  for (int i = blockIdx.x * BLK + threadIdx.x; i < n4; i += RED_BLOCKS * BLK) {
    v4f v = hu4[i];
    double a = (double)v.x, b = (double)v.y, c = (double)v.z, d = (double)v.w;
    s += a + b + c + d;
    q += a * a + b * b + c * c + d * d;
  }
  // tail (n % 4 != 0): fixed thread, fixed order -> deterministic
  if (blockIdx.x == 0 && threadIdx.x == 0) {
    for (int i = n4 << 2; i < n; ++i) {
      double v = (double)hu[i];
      s += v;
      q += v * v;
    }
  }
  ls[threadIdx.x] = s;
  lq[threadIdx.x] = q;
  __syncthreads();
  for (int off = BLK / 2; off > 0; off >>= 1) {
    if (threadIdx.x < off) {
      ls[threadIdx.x] += ls[threadIdx.x + off];
      lq[threadIdx.x] += lq[threadIdx.x + off];
    }
    __syncthreads();
  }
  if (threadIdx.x == 0) {
    part[blockIdx.x] = ls[0];
    part[RED_BLOCKS + blockIdx.x] = lq[0];
  }
}

// ---------------- K2: redundant final reduce + fused 2-hop GCN ----------------
// Per node u:
//   a_u = (sum_{v in N(u)} hu[v] - 4mu)*inv ; c_u = (hu[u]-mu)*inv
//   s_self(u) = sum_j relu(b1+a_u*Wn1+c_u*Ws1)_j * Wself2_j
//   for each v in N(u): recompute s_nei(v) the same way with a_v,c_v (2-hop gathers),
//   all four v packed in one v4f; lane-sum gives sum_v s_nei(v).
//   out[u] = 0.3*tanh(b2 + sum_v s_nei(v) + s_self(u))
__global__ void __launch_bounds__(BLK) k_main(
    const float* __restrict__ hu,
    const int* __restrict__ nbr,
    const float* __restrict__ Wn1,
    const float* __restrict__ Ws1,
    const float* __restrict__ B1,
    const float* __restrict__ Wn2,
    const float* __restrict__ Ws2,
    const float* __restrict__ B2,
    const double* __restrict__ part,
    float* __restrict__ out,
    int n) {
  // w4[j] = {Wn1[j], Ws1[j], Wn2[j], Ws2[j]}; wave-uniform b128 reads -> broadcast, conflict-free
  __shared__ v4f w4[HDIM];
  __shared__ float bb[HDIM];
  __shared__ double red_s[BLK];
  __shared__ double red_q[BLK];
  __shared__ float sstat[2];

  const int t = threadIdx.x;
  // ---- stage A: block-redundant final reduction (RED_BLOCKS == BLK) ----
  red_s[t] = part[t];
  red_q[t] = part[RED_BLOCKS + t];
  if (t < HDIM) {
    v4f w;
    w.x = Wn1[t];
    w.y = Ws1[t];
    w.z = Wn2[t];
    w.w = Ws2[t];
    w4[t] = w;
    bb[t] = B1[t];
  }
  __syncthreads();
  for (int off = BLK / 2; off > 0; off >>= 1) {
    if (t < off) {
      red_s[t] += red_s[t + off];
      red_q[t] += red_q[t + off];
    }
    __syncthreads();
  }
  if (t == 0) {
    double sum = red_s[0], sumsq = red_q[0];
    double mu = sum / (double)n;
    double var = (sumsq - sum * sum / (double)n) / (double)(n - 1);
    if (var < 0.0) var = 0.0;
    double sigma = sqrt(var) + 1e-8;  // unbiased std + EPS
    sstat[0] = (float)mu;
    sstat[1] = (float)(1.0 / sigma);
  }
  __syncthreads();

  // ---- stage B: per-node fused 2-hop compute ----
  const int u = blockIdx.x * BLK + t;
  if (u >= n) return;
  const float mu = sstat[0];
  const float inv = sstat[1];
  const v4i* nbr4 = (const v4i*)nbr;

  v4i nb = nbr4[u];  // coalesced
  // 1-hop hu
  float h0v = hu[nb.x], h1v = hu[nb.y], h2v = hu[nb.z], h3v = hu[nb.w];
  float h_u = hu[u];
  // neighbor adjacency (random int4 gathers over 16 MB; L2/L3)
  v4i nb0 = nbr4[nb.x];
  v4i nb1 = nbr4[nb.y];
  v4i nb2 = nbr4[nb.z];
  v4i nb3 = nbr4[nb.w];
  // 2-hop hu sums
  v4f hs;
  hs.x = (hu[nb0.x] + hu[nb0.y]) + (hu[nb0.z] + hu[nb0.w]);
  hs.y = (hu[nb1.x] + hu[nb1.y]) + (hu[nb1.z] + hu[nb1.w]);
  hs.z = (hu[nb2.x] + hu[nb2.y]) + (hu[nb2.z] + hu[nb2.w]);
  hs.w = (hu[nb3.x] + hu[nb3.y]) + (hu[nb3.z] + hu[nb3.w]);

  v4f hn = {h0v, h1v, h2v, h3v};
  v4f a4 = (hs - 4.0f * mu) * inv;   // a_v for the 4 neighbors
  v4f c4 = (hn - mu) * inv;          // c_v
  float a_u = (((h0v + h1v) + (h2v + h3v)) - 4.0f * mu) * inv;
  float c_u = (h_u - mu) * inv;

  v4f z = {0.0f, 0.0f, 0.0f, 0.0f};
  v4f sn4 = z;
  float ss = 0.0f;
#pragma unroll
  for (int j = 0; j < HDIM; ++j) {
    v4f w = w4[j];       // {wn1, ws1, wn2, ws2} broadcast
    float bj = bb[j];
    v4f tt = a4 * w.x + c4 * w.y + bj;            // packed fma (scalar splat)
    v4f r = __builtin_elementwise_max(tt, z);
    sn4 += r * w.z;                               // accumulate s_nei over 4 lanes
    float ts = fmaf(a_u, w.x, fmaf(c_u, w.y, bj));
    ss = fmaf(fmaxf(ts, 0.0f), w.w, ss);          // s_self
  }
  float d = B2[0] + ((sn4.x + sn4.y) + (sn4.z + sn4.w)) + ss;
  __builtin_nontemporal_store(0.3f * tanhf(d), out + u);
}

extern "C" void kernel_launch(void* const* d_in, const int* in_sizes, int n_in,
                              void* d_out, int out_size, void* d_ws, size_t ws_size,
                              hipStream_t stream) {
  const float* hu  = (const float*)d_in[0];
  const int*   nbr = (const int*)d_in[1];
  // d_in[2] = neighbor_offsets: fixed-degree-4 CSR (arange*4), not needed.
  const float* Wn1 = (const float*)d_in[3];
  const float* Ws1 = (const float*)d_in[4];
  const float* B1  = (const float*)d_in[5];
  const float* Wn2 = (const float*)d_in[6];
  const float* Ws2 = (const float*)d_in[7];
  const float* B2  = (const float*)d_in[8];
  float* out = (float*)d_out;
  const int n = in_sizes[0];

  double* part = (double*)d_ws;  // 2*RED_BLOCKS*8 = 4 KiB

  k_reduce_partial<<<RED_BLOCKS, BLK, 0, stream>>>(hu, n, part);
  int blocks = (n + BLK - 1) / BLK;
  k_main<<<blocks, BLK, 0, stream>>>(hu, nbr, Wn1, Ws1, B1, Wn2, Ws2, B2,
                                     part, out, n);
}

// Round 6
// 62.001 us; speedup vs baseline: 2.7354x; 2.7354x over previous
//
#include <hip/hip_runtime.h>
#include <math.h>

#define RED_BLOCKS 256
#define BLK 256
#define HDIM 64
#define NPT 4                    // nodes per thread (gather MLP)
#define BNODES (BLK * NPT)       // nodes per block

typedef int   v4i __attribute__((ext_vector_type(4)));
typedef float v4f __attribute__((ext_vector_type(4)));

// ---------------- K1: per-block partial sum / sumsq (f64, deterministic) ----------------
__global__ void __launch_bounds__(BLK) k_reduce_partial(const float* __restrict__ hu, int n,
                                                        double* __restrict__ part) {
  __shared__ double ls[BLK];
  __shared__ double lq[BLK];
  const v4f* hu4 = (const v4f*)hu;
  const int n4 = n >> 2;
  double s = 0.0, q = 0.0;
  for (int i = blockIdx.x * BLK + threadIdx.x; i < n4; i += RED_BLOCKS * BLK) {
    v4f v = hu4[i];
    double a = (double)v.x, b = (double)v.y, c = (double)v.z, d = (double)v.w;
    s += a + b + c + d;
    q += a * a + b * b + c * c + d * d;
  }
  if (blockIdx.x == 0 && threadIdx.x == 0) {  // tail, fixed order -> deterministic
    for (int i = n4 << 2; i < n; ++i) {
      double v = (double)hu[i];
      s += v;
      q += v * v;
    }
  }
  ls[threadIdx.x] = s;
  lq[threadIdx.x] = q;
  __syncthreads();
  for (int off = BLK / 2; off > 0; off >>= 1) {
    if (threadIdx.x < off) {
      ls[threadIdx.x] += ls[threadIdx.x + off];
      lq[threadIdx.x] += lq[threadIdx.x + off];
    }
    __syncthreads();
  }
  if (threadIdx.x == 0) {
    part[blockIdx.x] = ls[0];
    part[RED_BLOCKS + blockIdx.x] = lq[0];
  }
}

// ---------------- K2: block-redundant stats finalize + layer1 (4 nodes/thread) ----------------
// snei[u] = sum_j relu(b1 + a_u*Wn1 + c_u*Ws1)_j * Wnei2_j
// sself[u] = same with Wself2_j
__global__ void __launch_bounds__(BLK) k_layer1(
    const float* __restrict__ hu,
    const int* __restrict__ nbr,
    const float* __restrict__ Wn1,
    const float* __restrict__ Ws1,
    const float* __restrict__ B1,
    const float* __restrict__ Wn2,
    const float* __restrict__ Ws2,
    const double* __restrict__ part,
    float* __restrict__ snei,
    float* __restrict__ sself,
    int n) {
  __shared__ v4f w4[HDIM];     // {Wn1, Ws1, Wn2, Ws2}
  __shared__ float bb[HDIM];
  __shared__ double red_s[BLK];
  __shared__ double red_q[BLK];
  __shared__ float sstat[2];

  const int t = threadIdx.x;
  red_s[t] = part[t];
  red_q[t] = part[RED_BLOCKS + t];
  if (t < HDIM) {
    v4f w;
    w.x = Wn1[t]; w.y = Ws1[t]; w.z = Wn2[t]; w.w = Ws2[t];
    w4[t] = w;
    bb[t] = B1[t];
  }
  __syncthreads();
  for (int off = BLK / 2; off > 0; off >>= 1) {
    if (t < off) {
      red_s[t] += red_s[t + off];
      red_q[t] += red_q[t + off];
    }
    __syncthreads();
  }
  if (t == 0) {
    double sum = red_s[0], sumsq = red_q[0];
    double mu = sum / (double)n;
    double var = (sumsq - sum * sum / (double)n) / (double)(n - 1);
    if (var < 0.0) var = 0.0;
    double sigma = sqrt(var) + 1e-8;  // unbiased std + EPS
    sstat[0] = (float)mu;
    sstat[1] = (float)(1.0 / sigma);
  }
  __syncthreads();

  const int base = blockIdx.x * BNODES + t;
  const v4i* nbr4 = (const v4i*)nbr;

  // branch-free clamped indices so ALL loads issue unconditionally (max MLP)
  int u[NPT];
  bool ok[NPT];
#pragma unroll
  for (int k = 0; k < NPT; ++k) {
    int uu = base + k * BLK;
    ok[k] = uu < n;
    u[k] = ok[k] ? uu : (n - 1);
  }
  v4i nb[NPT];
#pragma unroll
  for (int k = 0; k < NPT; ++k) nb[k] = __builtin_nontemporal_load(nbr4 + u[k]);
  float hself[NPT];
#pragma unroll
  for (int k = 0; k < NPT; ++k) hself[k] = hu[u[k]];
  // 16 independent random gathers in flight
  float g[NPT][4];
#pragma unroll
  for (int k = 0; k < NPT; ++k) {
    g[k][0] = hu[nb[k].x];
    g[k][1] = hu[nb[k].y];
    g[k][2] = hu[nb[k].z];
    g[k][3] = hu[nb[k].w];
  }

  const float mu = sstat[0];
  const float inv = sstat[1];
  v4f a4, c4;
  a4.x = ((g[0][0] + g[0][1]) + (g[0][2] + g[0][3]) - 4.0f * mu) * inv;
  a4.y = ((g[1][0] + g[1][1]) + (g[1][2] + g[1][3]) - 4.0f * mu) * inv;
  a4.z = ((g[2][0] + g[2][1]) + (g[2][2] + g[2][3]) - 4.0f * mu) * inv;
  a4.w = ((g[3][0] + g[3][1]) + (g[3][2] + g[3][3]) - 4.0f * mu) * inv;
  c4.x = (hself[0] - mu) * inv;
  c4.y = (hself[1] - mu) * inv;
  c4.z = (hself[2] - mu) * inv;
  c4.w = (hself[3] - mu) * inv;

  v4f z = {0.0f, 0.0f, 0.0f, 0.0f};
  v4f sn4 = z, ss4 = z;  // lane = node
#pragma unroll
  for (int j = 0; j < HDIM; ++j) {
    v4f w = w4[j];
    v4f tt = a4 * w.x + c4 * w.y + bb[j];
    v4f r = __builtin_elementwise_max(tt, z);
    sn4 += r * w.z;
    ss4 += r * w.w;
  }
  // coalesced per-k stores (thread t -> base + k*BLK)
  if (ok[0]) { snei[u[0]] = sn4.x; __builtin_nontemporal_store(ss4.x, sself + u[0]); }
  if (ok[1]) { snei[u[1]] = sn4.y; __builtin_nontemporal_store(ss4.y, sself + u[1]); }
  if (ok[2]) { snei[u[2]] = sn4.z; __builtin_nontemporal_store(ss4.z, sself + u[2]); }
  if (ok[3]) { snei[u[3]] = sn4.w; __builtin_nontemporal_store(ss4.w, sself + u[3]); }
}

// ---------------- K3: layer2 gather + tanh (4 nodes/thread) ----------------
__global__ void __launch_bounds__(BLK) k_layer2(
    const int* __restrict__ nbr,
    const float* __restrict__ snei,
    const float* __restrict__ sself,
    const float* __restrict__ B2,
    float* __restrict__ out,
    int n) {
  const int t = threadIdx.x;
  const int base = blockIdx.x * BNODES + t;
  const v4i* nbr4 = (const v4i*)nbr;

  int u[NPT];
  bool ok[NPT];
#pragma unroll
  for (int k = 0; k < NPT; ++k) {
    int uu = base + k * BLK;
    ok[k] = uu < n;
    u[k] = ok[k] ? uu : (n - 1);
  }
  v4i nb[NPT];
#pragma unroll
  for (int k = 0; k < NPT; ++k) nb[k] = __builtin_nontemporal_load(nbr4 + u[k]);
  float ss[NPT];
#pragma unroll
  for (int k = 0; k < NPT; ++k) ss[k] = __builtin_nontemporal_load(sself + u[k]);
  // 16 independent random gathers in flight
  float g[NPT][4];
#pragma unroll
  for (int k = 0; k < NPT; ++k) {
    g[k][0] = snei[nb[k].x];
    g[k][1] = snei[nb[k].y];
    g[k][2] = snei[nb[k].z];
    g[k][3] = snei[nb[k].w];
  }
  const float b2v = B2[0];
#pragma unroll
  for (int k = 0; k < NPT; ++k) {
    if (ok[k]) {
      float d = b2v + ((g[k][0] + g[k][1]) + (g[k][2] + g[k][3])) + ss[k];
      __builtin_nontemporal_store(0.3f * tanhf(d), out + u[k]);
    }
  }
}

extern "C" void kernel_launch(void* const* d_in, const int* in_sizes, int n_in,
                              void* d_out, int out_size, void* d_ws, size_t ws_size,
                              hipStream_t stream) {
  const float* hu  = (const float*)d_in[0];
  const int*   nbr = (const int*)d_in[1];
  // d_in[2] = neighbor_offsets: fixed degree-4 CSR, not needed.
  const float* Wn1 = (const float*)d_in[3];
  const float* Ws1 = (const float*)d_in[4];
  const float* B1  = (const float*)d_in[5];
  const float* Wn2 = (const float*)d_in[6];
  const float* Ws2 = (const float*)d_in[7];
  const float* B2  = (const float*)d_in[8];
  float* out = (float*)d_out;
  const int n = in_sizes[0];

  char* ws = (char*)d_ws;
  double* part = (double*)ws;                 // 2*256*8 = 4 KiB
  float* snei  = (float*)(ws + 8192);         // n*4 B
  float* sself = snei + n;                    // n*4 B

  k_reduce_partial<<<RED_BLOCKS, BLK, 0, stream>>>(hu, n, part);
  int blocks = (n + BNODES - 1) / BNODES;
  k_layer1<<<blocks, BLK, 0, stream>>>(hu, nbr, Wn1, Ws1, B1, Wn2, Ws2, part,
                                       snei, sself, n);
  k_layer2<<<blocks, BLK, 0, stream>>>(nbr, snei, sself, B2, out, n);
}

// Round 7
// 61.816 us; speedup vs baseline: 2.7436x; 1.0030x over previous
//
#include <hip/hip_runtime.h>
#include <math.h>

#define RED_BLOCKS 256
#define BLK 256
#define HDIM 64
#define NPT 4                    // nodes per thread
#define BNODES (BLK * NPT)       // nodes per block
#define NPASS 4                  // gather target-range blocking (1 MB per pass)

typedef int   v4i __attribute__((ext_vector_type(4)));
typedef float v4f __attribute__((ext_vector_type(4)));

// ---------------- K1: per-block partial sum / sumsq (f64, deterministic) ----------------
__global__ void __launch_bounds__(BLK) k_reduce_partial(const float* __restrict__ hu, int n,
                                                        double* __restrict__ part) {
  __shared__ double ls[BLK];
  __shared__ double lq[BLK];
  const v4f* hu4 = (const v4f*)hu;
  const int n4 = n >> 2;
  double s = 0.0, q = 0.0;
  for (int i = blockIdx.x * BLK + threadIdx.x; i < n4; i += RED_BLOCKS * BLK) {
    v4f v = hu4[i];
    double a = (double)v.x, b = (double)v.y, c = (double)v.z, d = (double)v.w;
    s += a + b + c + d;
    q += a * a + b * b + c * c + d * d;
  }
  if (blockIdx.x == 0 && threadIdx.x == 0) {  // tail, fixed order -> deterministic
    for (int i = n4 << 2; i < n; ++i) {
      double v = (double)hu[i];
      s += v;
      q += v * v;
    }
  }
  ls[threadIdx.x] = s;
  lq[threadIdx.x] = q;
  __syncthreads();
  for (int off = BLK / 2; off > 0; off >>= 1) {
    if (threadIdx.x < off) {
      ls[threadIdx.x] += ls[threadIdx.x + off];
      lq[threadIdx.x] += lq[threadIdx.x + off];
    }
    __syncthreads();
  }
  if (threadIdx.x == 0) {
    part[blockIdx.x] = ls[0];
    part[RED_BLOCKS + blockIdx.x] = lq[0];
  }
}

// masked range-gather: acc += arr[v] iff lo <= v < hi (exec-masked load; no request
// for inactive lanes). if-guard (not ?:) so the backend cannot speculate the load.
__device__ __forceinline__ void range_gather(const float* __restrict__ arr, int v,
                                             int lo, int hi, float& acc) {
  if (v >= lo && v < hi) acc += arr[v];
}

// ---------------- K2: block-redundant stats finalize + layer1 (range-blocked hu gather) ----
__global__ void __launch_bounds__(BLK) k_layer1(
    const float* __restrict__ hu,
    const int* __restrict__ nbr,
    const float* __restrict__ Wn1,
    const float* __restrict__ Ws1,
    const float* __restrict__ B1,
    const float* __restrict__ Wn2,
    const float* __restrict__ Ws2,
    const double* __restrict__ part,
    float* __restrict__ snei,
    float* __restrict__ sself,
    int n) {
  __shared__ v4f w4[HDIM];     // {Wn1, Ws1, Wn2, Ws2}
  __shared__ float bb[HDIM];
  __shared__ double red_s[BLK];
  __shared__ double red_q[BLK];
  __shared__ float sstat[2];

  const int t = threadIdx.x;
  red_s[t] = part[t];
  red_q[t] = part[RED_BLOCKS + t];
  if (t < HDIM) {
    v4f w;
    w.x = Wn1[t]; w.y = Ws1[t]; w.z = Wn2[t]; w.w = Ws2[t];
    w4[t] = w;
    bb[t] = B1[t];
  }
  __syncthreads();
  for (int off = BLK / 2; off > 0; off >>= 1) {
    if (t < off) {
      red_s[t] += red_s[t + off];
      red_q[t] += red_q[t + off];
    }
    __syncthreads();
  }
  if (t == 0) {
    double sum = red_s[0], sumsq = red_q[0];
    double mu = sum / (double)n;
    double var = (sumsq - sum * sum / (double)n) / (double)(n - 1);
    if (var < 0.0) var = 0.0;
    double sigma = sqrt(var) + 1e-8;  // unbiased std + EPS
    sstat[0] = (float)mu;
    sstat[1] = (float)(1.0 / sigma);
  }
  __syncthreads();

  const int base = blockIdx.x * BNODES + t;
  const v4i* nbr4 = (const v4i*)nbr;

  int u[NPT];
  bool ok[NPT];
#pragma unroll
  for (int k = 0; k < NPT; ++k) {
    int uu = base + k * BLK;
    ok[k] = uu < n;
    u[k] = ok[k] ? uu : (n - 1);
  }
  v4i nb[NPT];
#pragma unroll
  for (int k = 0; k < NPT; ++k) nb[k] = __builtin_nontemporal_load(nbr4 + u[k]);
  float hself[NPT];
#pragma unroll
  for (int k = 0; k < NPT; ++k) hself[k] = hu[u[k]];

  // range-blocked random gather of hu: per pass the device-wide active target
  // footprint is n/NPASS*4B (1 MB) -> stays resident in every XCD's L2.
  float hs[NPT];
#pragma unroll
  for (int k = 0; k < NPT; ++k) hs[k] = 0.0f;
#pragma unroll
  for (int p = 0; p < NPASS; ++p) {
    const int lo = (int)(((long long)n * p) / NPASS);
    const int hi = (int)(((long long)n * (p + 1)) / NPASS);
#pragma unroll
    for (int k = 0; k < NPT; ++k) {
      range_gather(hu, nb[k].x, lo, hi, hs[k]);
      range_gather(hu, nb[k].y, lo, hi, hs[k]);
      range_gather(hu, nb[k].z, lo, hi, hs[k]);
      range_gather(hu, nb[k].w, lo, hi, hs[k]);
    }
  }

  const float mu = sstat[0];
  const float inv = sstat[1];
  v4f a4, c4;
  a4.x = (hs[0] - 4.0f * mu) * inv;
  a4.y = (hs[1] - 4.0f * mu) * inv;
  a4.z = (hs[2] - 4.0f * mu) * inv;
  a4.w = (hs[3] - 4.0f * mu) * inv;
  c4.x = (hself[0] - mu) * inv;
  c4.y = (hself[1] - mu) * inv;
  c4.z = (hself[2] - mu) * inv;
  c4.w = (hself[3] - mu) * inv;

  v4f z = {0.0f, 0.0f, 0.0f, 0.0f};
  v4f sn4 = z, ss4 = z;  // lane = node k
#pragma unroll
  for (int j = 0; j < HDIM; ++j) {
    v4f w = w4[j];
    v4f tt = a4 * w.x + c4 * w.y + bb[j];
    v4f r = __builtin_elementwise_max(tt, z);
    sn4 += r * w.z;
    ss4 += r * w.w;
  }
  if (ok[0]) { snei[u[0]] = sn4.x; __builtin_nontemporal_store(ss4.x, sself + u[0]); }
  if (ok[1]) { snei[u[1]] = sn4.y; __builtin_nontemporal_store(ss4.y, sself + u[1]); }
  if (ok[2]) { snei[u[2]] = sn4.z; __builtin_nontemporal_store(ss4.z, sself + u[2]); }
  if (ok[3]) { snei[u[3]] = sn4.w; __builtin_nontemporal_store(ss4.w, sself + u[3]); }
}

// ---------------- K3: layer2 (range-blocked snei gather) + tanh ----------------
__global__ void __launch_bounds__(BLK) k_layer2(
    const int* __restrict__ nbr,
    const float* __restrict__ snei,
    const float* __restrict__ sself,
    const float* __restrict__ B2,
    float* __restrict__ out,
    int n) {
  const int t = threadIdx.x;
  const int base = blockIdx.x * BNODES + t;
  const v4i* nbr4 = (const v4i*)nbr;

  int u[NPT];
  bool ok[NPT];
#pragma unroll
  for (int k = 0; k < NPT; ++k) {
    int uu = base + k * BLK;
    ok[k] = uu < n;
    u[k] = ok[k] ? uu : (n - 1);
  }
  v4i nb[NPT];
#pragma unroll
  for (int k = 0; k < NPT; ++k) nb[k] = __builtin_nontemporal_load(nbr4 + u[k]);
  float ss[NPT];
#pragma unroll
  for (int k = 0; k < NPT; ++k) ss[k] = __builtin_nontemporal_load(sself + u[k]);

  float acc[NPT];
#pragma unroll
  for (int k = 0; k < NPT; ++k) acc[k] = 0.0f;
#pragma unroll
  for (int p = 0; p < NPASS; ++p) {
    const int lo = (int)(((long long)n * p) / NPASS);
    const int hi = (int)(((long long)n * (p + 1)) / NPASS);
#pragma unroll
    for (int k = 0; k < NPT; ++k) {
      range_gather(snei, nb[k].x, lo, hi, acc[k]);
      range_gather(snei, nb[k].y, lo, hi, acc[k]);
      range_gather(snei, nb[k].z, lo, hi, acc[k]);
      range_gather(snei, nb[k].w, lo, hi, acc[k]);
    }
  }

  const float b2v = B2[0];
#pragma unroll
  for (int k = 0; k < NPT; ++k) {
    if (ok[k]) {
      float d = b2v + acc[k] + ss[k];
      __builtin_nontemporal_store(0.3f * tanhf(d), out + u[k]);
    }
  }
}

extern "C" void kernel_launch(void* const* d_in, const int* in_sizes, int n_in,
                              void* d_out, int out_size, void* d_ws, size_t ws_size,
                              hipStream_t stream) {
  const float* hu  = (const float*)d_in[0];
  const int*   nbr = (const int*)d_in[1];
  // d_in[2] = neighbor_offsets: fixed degree-4 CSR, not needed.
  const float* Wn1 = (const float*)d_in[3];
  const float* Ws1 = (const float*)d_in[4];
  const float* B1  = (const float*)d_in[5];
  const float* Wn2 = (const float*)d_in[6];
  const float* Ws2 = (const float*)d_in[7];
  const float* B2  = (const float*)d_in[8];
  float* out = (float*)d_out;
  const int n = in_sizes[0];

  char* ws = (char*)d_ws;
  double* part = (double*)ws;                 // 2*256*8 = 4 KiB
  float* snei  = (float*)(ws + 8192);         // n*4 B
  float* sself = snei + n;                    // n*4 B

  k_reduce_partial<<<RED_BLOCKS, BLK, 0, stream>>>(hu, n, part);
  int blocks = (n + BNODES - 1) / BNODES;
  k_layer1<<<blocks, BLK, 0, stream>>>(hu, nbr, Wn1, Ws1, B1, Wn2, Ws2, part,
                                       snei, sself, n);
  k_layer2<<<blocks, BLK, 0, stream>>>(nbr, snei, sself, B2, out, n);
}